// Round 1
// baseline (2142.284 us; speedup 1.0000x reference)
//
#include <hip/hip_runtime.h>
#include <cmath>

// Problem constants (B, L, D, H) = (256, 32, 512, 512)
#define B_   256
#define L_   32
#define D_   512
#define H_   512
#define NH5  2560   // 5*H
#define SCALE 0.044194173824159216f  // 1/sqrt(H)

// ---------------- persistent device state (re-initialized every launch) ----
__device__ float g_h [B_*L_*H_];     // [b][slot][j] node hidden
__device__ float g_c [B_*L_*H_];     // [b][slot][j] node cell
__device__ float g_al[B_*L_*NH5];    // [b][slot][k] Wl @ h_slot  (left-child contribution)
__device__ float g_ar[B_*L_*NH5];    // [b][slot][k] Wr @ h_slot  (right-child contribution)
__device__ float g_logit[B_*L_];     // pair logit keyed by LEFT slot
__device__ int   g_list[B_*L_];      // active slot list (sequence order)
__device__ int   g_count[B_];        // active node count
__device__ int   g_merged[B_];       // slot merged last iter (-1 inactive, -2 init)
__device__ int   g_mpos[B_];         // list position of last merge

// ---------------- generic fp32 NT GEMM: C[m,n] = sum_k A[m,k]*B[n,k] -------
// MODE 0: word GEMM   A=x(arg)        B=W_word rows     C-> g_h | g_c   (+b_word)
// MODE 1: leaf-a GEMM A=g_h           B=W_comp slices   C-> g_al | g_ar
// MODE 2: iter-a GEMM A=g_h[gathered] B=W_comp slices   C-> g_al | g_ar (masked rows)
template<int BM,int BN,int BK,int TM,int TN,int MODE>
__global__ __launch_bounds__(256) void gemm_nt(
    const float* __restrict__ Aext,
    const float* __restrict__ Bm,
    const float* __restrict__ bias,
    int K)
{
  constexpr int TX = BN / TN;
  constexpr int TY = BM / TM;
  static_assert(TX * TY == 256, "block=256");
  static_assert(BM * BK == 1024 && BN * BK == 1024, "one float4 per thread staging");

  const int tid = threadIdx.x;
  const int w = tid >> 6, l = tid & 63;
  // 2x2 wave arrangement: 8 tx x 8 ty per wave -> 2-way-max LDS bank aliasing (free)
  const int tx = (w & 1) * 8 + (l & 7);    // 0..15 (n dir)
  const int ty = (w >> 1) * 8 + (l >> 3);  // 0..15 (m dir)
  const int m0 = blockIdx.y * BM;
  const int n0 = blockIdx.x * BN;

  __shared__ float As[BK][BM];
  __shared__ float Bs[BK][BN];

  constexpr int QA = BK / 4;
  const int ra = tid / QA, qa = tid % QA;

  const float* Abase = (MODE == 0) ? Aext : g_h;
  const float* aptr;
  if (MODE == 2) {
    int mrow = m0 + ra;                 // batch id
    int slot = g_merged[mrow];
    if (slot < 0) slot = 0;             // inactive: load valid data, stores masked later
    aptr = Abase + (size_t)(mrow * L_ + slot) * H_ + qa * 4;
  } else {
    aptr = Abase + (size_t)(m0 + ra) * K + qa * 4;
  }
  const float* bptr;
  {
    int nrow = n0 + ra;
    if (MODE == 0) {
      bptr = Bm + (size_t)nrow * K + qa * 4;
    } else {
      // W_comp is (2560 x 1024) row-major; al-part uses cols [0,512), ar-part cols [512,1024)
      bptr = Bm + (nrow < NH5 ? (size_t)nrow * 1024
                              : (size_t)(nrow - NH5) * 1024 + 512) + qa * 4;
    }
  }

  float acc[TM][TN] = {};

  for (int k0 = 0; k0 < K; k0 += BK) {
    float4 av = *(const float4*)(aptr + k0);
    float4 bv = *(const float4*)(bptr + k0);
    __syncthreads();
    As[qa*4+0][ra] = av.x; As[qa*4+1][ra] = av.y;
    As[qa*4+2][ra] = av.z; As[qa*4+3][ra] = av.w;
    Bs[qa*4+0][ra] = bv.x; Bs[qa*4+1][ra] = bv.y;
    Bs[qa*4+2][ra] = bv.z; Bs[qa*4+3][ra] = bv.w;
    __syncthreads();
#pragma unroll
    for (int k = 0; k < BK; k++) {
      float af[TM], bf[TN];
#pragma unroll
      for (int c = 0; c < TM/4; c++) {
        float4 t = *(const float4*)&As[k][ty*TM + 4*c];
        af[4*c+0]=t.x; af[4*c+1]=t.y; af[4*c+2]=t.z; af[4*c+3]=t.w;
      }
#pragma unroll
      for (int c = 0; c < TN/4; c++) {
        float4 t = *(const float4*)&Bs[k][tx*TN + 4*c];
        bf[4*c+0]=t.x; bf[4*c+1]=t.y; bf[4*c+2]=t.z; bf[4*c+3]=t.w;
      }
#pragma unroll
      for (int i = 0; i < TM; i++)
#pragma unroll
        for (int j = 0; j < TN; j++)
          acc[i][j] = fmaf(af[i], bf[j], acc[i][j]);
    }
  }

#pragma unroll
  for (int i = 0; i < TM; i++) {
    int m = m0 + ty*TM + i;
    int crow = m;
    if (MODE == 2) {
      int slot = g_merged[m];
      if (slot < 0) continue;           // inactive batch: no store
      crow = m * L_ + slot;
    }
#pragma unroll
    for (int j = 0; j < TN; j++) {
      int n = n0 + tx*TN + j;
      float v = acc[i][j];
      if (bias) v += bias[n];
      if (MODE == 0) {
        if (n < H_) g_h[(size_t)crow*H_ + n]        = v;
        else        g_c[(size_t)crow*H_ + (n - H_)] = v;
      } else {
        if (n < NH5) g_al[(size_t)crow*NH5 + n]         = v;
        else         g_ar[(size_t)crow*NH5 + (n - NH5)] = v;
      }
    }
  }
}

// ---------------- elementwise compose + logit ------------------------------
__device__ __forceinline__ float sigm(float x) { return 1.0f / (1.0f + expf(-x)); }

__device__ __forceinline__ float block_sum(float v, float* sred) {
#pragma unroll
  for (int off = 32; off > 0; off >>= 1) v += __shfl_down(v, off, 64);
  int w = threadIdx.x >> 6;
  if ((threadIdx.x & 63) == 0) sred[w] = v;
  __syncthreads();
  float r = sred[0] + sred[1] + sred[2] + sred[3];
  __syncthreads();   // protect sred for next call
  return r;
}

// Compose pair (slot sl, slot sr) of batch b from cached a_l/a_r.
// If store_hc: write merged h,c into slot sl. Returns q . h_new (all threads).
__device__ float compose_pair(int b, int sl, int sr, bool store_hc,
                              const float* __restrict__ bc,
                              const float* __restrict__ q,
                              float* sred)
{
  const float* al = g_al + (size_t)(b*L_ + sl)*NH5;
  const float* ar = g_ar + (size_t)(b*L_ + sr)*NH5;
  float*       cl = g_c  + (size_t)(b*L_ + sl)*H_;
  const float* cr = g_c  + (size_t)(b*L_ + sr)*H_;
  float*       hl = g_h  + (size_t)(b*L_ + sl)*H_;
  float part = 0.f;
  for (int j = threadIdx.x; j < H_; j += 256) {
    float vi  = al[j]        + ar[j]        + bc[j];
    float vfl = al[H_+j]     + ar[H_+j]     + bc[H_+j];
    float vfr = al[2*H_+j]   + ar[2*H_+j]   + bc[2*H_+j];
    float vu  = al[3*H_+j]   + ar[3*H_+j]   + bc[3*H_+j];
    float vo  = al[4*H_+j]   + ar[4*H_+j]   + bc[4*H_+j];
    float c = cl[j]*sigm(vfl+1.f) + cr[j]*sigm(vfr+1.f) + tanhf(vu)*sigm(vi);
    float h = sigm(vo)*tanhf(c);
    if (store_hc) { cl[j] = c; hl[j] = h; }   // same-thread j: no RAW hazard
    part += q[j]*h;
  }
  return block_sum(part, sred);
}

__global__ __launch_bounds__(64) void init_state(const int* __restrict__ length) {
  int b = blockIdx.x, t = threadIdx.x;
  if (t < L_) g_list[b*L_ + t] = t;
  if (t == 0) { g_count[b] = length[b]; g_merged[b] = -2; g_mpos[b] = 0; }
}

__global__ __launch_bounds__(256) void iter0_logits(const float* __restrict__ bc,
                                                    const float* __restrict__ q) {
  __shared__ float sred[4];
  int p = blockIdx.x, b = blockIdx.y;   // pair p = (slot p, slot p+1)
  float lg = compose_pair(b, p, p+1, false, bc, q, sred);
  if (threadIdx.x == 0) g_logit[b*L_ + p] = lg * SCALE;
}

__global__ __launch_bounds__(256) void select_merge(int iter,
    const int* __restrict__ length,
    const float* __restrict__ bc,
    const float* __restrict__ q)
{
  __shared__ float sred[4];
  __shared__ int s_sel[3];
  int b = blockIdx.x, tid = threadIdx.x;
  int m     = g_count[b];
  int pslot = g_merged[b];
  int ppos  = g_mpos[b];
  const int* list = g_list + b*L_;

  // Refresh logits of the (<=2) pairs whose child changed last iteration.
  if (iter > 0 && pslot >= 0) {
    if (ppos > 0) {
      int sl = list[ppos-1], sr = list[ppos];
      float lg = compose_pair(b, sl, sr, false, bc, q, sred);
      if (tid == 0) g_logit[b*L_ + sl] = lg * SCALE;
    }
    if (ppos < m-1) {
      int sl = list[ppos], sr = list[ppos+1];
      float lg = compose_pair(b, sl, sr, false, bc, q, sred);
      if (tid == 0) g_logit[b*L_ + sl] = lg * SCALE;
    }
  }

  bool active = iter < (length[b] - 1);
  if (!active) { if (tid == 0) g_merged[b] = -1; return; }

  __syncthreads();
  if (tid == 0) {
    float best = -1e30f; int bi = 0;
    for (int n = 0; n < m-1; n++) {           // list order == sequence order (first-max)
      float lg = g_logit[b*L_ + list[n]];
      if (lg > best) { best = lg; bi = n; }
    }
    s_sel[0] = bi; s_sel[1] = list[bi]; s_sel[2] = list[bi+1];
  }
  __syncthreads();
  int pos = s_sel[0], sl = s_sel[1], sr = s_sel[2];
  compose_pair(b, sl, sr, true, bc, q, sred);  // write merged h,c into slot sl
  if (tid == 0) {
    for (int n = pos+1; n < m-1; n++) g_list[b*L_ + n] = g_list[b*L_ + n+1];
    g_count[b]  = m - 1;
    g_merged[b] = sl;
    g_mpos[b]   = pos;
  }
}

__global__ __launch_bounds__(256) void write_out(float* __restrict__ out) {
  int b = blockIdx.x;
  for (int j = threadIdx.x; j < H_; j += 256)
    out[(size_t)b*H_ + j] = g_h[(size_t)(b*L_)*H_ + j];   // node 0 always slot 0
}

// ---------------------------------------------------------------------------
extern "C" void kernel_launch(void* const* d_in, const int* in_sizes, int n_in,
                              void* d_out, int out_size, void* d_ws, size_t ws_size,
                              hipStream_t stream)
{
  (void)in_sizes; (void)n_in; (void)out_size; (void)d_ws; (void)ws_size;
  const float* x      = (const float*)d_in[0];
  const int*   length = (const int*)  d_in[1];
  const float* W_word = (const float*)d_in[2];
  const float* b_word = (const float*)d_in[3];
  const float* W_comp = (const float*)d_in[4];
  const float* b_comp = (const float*)d_in[5];
  const float* q      = (const float*)d_in[6];
  float* out = (float*)d_out;

  init_state<<<B_, 64, 0, stream>>>(length);

  // hc = x @ W_word^T + b_word  ->  g_h | g_c    (M=8192, N=1024, K=512)
  gemm_nt<128,128,8,8,8,0><<<dim3(1024/128, (B_*L_)/128), 256, 0, stream>>>(
      x, W_word, b_word, D_);

  // leaf a_l/a_r = h_leaf @ [Wl;Wr]^T            (M=8192, N=5120, K=512)
  gemm_nt<128,128,8,8,8,1><<<dim3((2*NH5)/128, (B_*L_)/128), 256, 0, stream>>>(
      nullptr, W_comp, nullptr, H_);

  // iteration-0 logits for all 31 adjacent pairs
  iter0_logits<<<dim3(L_-1, B_), 256, 0, stream>>>(b_comp, q);

  for (int i = 0; i < L_-1; i++) {
    select_merge<<<B_, 256, 0, stream>>>(i, length, b_comp, q);
    if (i < L_-2) {
      // a_l/a_r for the newly merged node       (M=256, N=5120, K=512)
      gemm_nt<64,64,16,4,4,2><<<dim3((2*NH5)/64, B_/64), 256, 0, stream>>>(
          nullptr, W_comp, nullptr, H_);
    }
  }

  write_out<<<B_, 256, 0, stream>>>(out);
}